// Round 3
// baseline (468.642 us; speedup 1.0000x reference)
//
#include <hip/hip_runtime.h>
#include <hip/hip_bf16.h>
#include <math.h>

// Problem constants: B=4, T=512, S=1024, H=768, V=50257
#define BB 4
#define TT 512
#define SS 1024
#define HH 768
#define VV 50257
#define NW 1571            // ceil(V/32) bitmap words (setup kernel only)
#define CHUNK 2048         // columns per zero+scatter chunk (8KB)
#define NCH 25             // ceil(V/CHUNK)

// ---------------------------------------------------------------------------
// Kernel A: projections (unchanged — verified absmax 0).
// ---------------------------------------------------------------------------
__global__ __launch_bounds__(256) void proj_kernel(
    const float* __restrict__ src, const float* __restrict__ tgt,
    const float* __restrict__ W, const float* __restrict__ bptr,
    float* __restrict__ src_proj, float* __restrict__ tgt_proj)
{
    const int wave = threadIdx.x >> 6;
    const int lane = threadIdx.x & 63;
    const int row  = blockIdx.x * 4 + wave;   // 0 .. 6143

    const float* vec;
    const float* w;
    if (row < BB * SS) { vec = src + (size_t)row * HH;            w = W; }
    else               { vec = tgt + (size_t)(row - BB*SS) * HH;  w = W + HH; }
    const float4* v4 = (const float4*)vec;
    const float4* w4 = (const float4*)w;

    float acc = 0.f;
#pragma unroll
    for (int k = 0; k < 3; ++k) {
        float4 a = v4[k * 64 + lane];
        float4 b = w4[k * 64 + lane];
        acc += a.x * b.x + a.y * b.y + a.z * b.z + a.w * b.w;
    }
#pragma unroll
    for (int off = 32; off > 0; off >>= 1) acc += __shfl_down(acc, off);
    if (lane == 0) {
        if (row < BB * SS) src_proj[row] = acc;
        else               tgt_proj[row - BB * SS] = acc + bptr[0];
    }
}

// ---------------------------------------------------------------------------
// Kernel S: per-batch setup. One block per batch.
//   rank_g[b,s]: dense slot of ids[b,s] among the batch's unique ids
//                (ordered by id value)
//   col_g[b,r] : inverse map — the id (column) owning rank r, sorted
//                ascending; 0xFFFF sentinel for r >= nuniq
// ---------------------------------------------------------------------------
__global__ __launch_bounds__(256) void batch_setup(
    const int* __restrict__ ids,
    unsigned short* __restrict__ rank_g,  // [B, S]
    unsigned short* __restrict__ col_g)   // [B, S]
{
    __shared__ unsigned bm[NW];
    __shared__ unsigned pre[NW];
    __shared__ unsigned scan[256];
    __shared__ unsigned short coll[SS];
    const int b = blockIdx.x, tid = threadIdx.x;

    for (int i = tid; i < NW; i += 256) bm[i] = 0u;
    for (int i = tid; i < SS; i += 256) coll[i] = 0xFFFFu;
    __syncthreads();
    const int* idb = ids + b * SS;
    for (int s = tid; s < SS; s += 256) {
        const int v = idb[s];
        atomicOr(&bm[v >> 5], 1u << (v & 31));
    }
    __syncthreads();

    // Each thread owns 7 consecutive words (256*7 = 1792 >= 1571).
    unsigned cnt[7];
    unsigned local = 0;
    const int w0 = tid * 7;
#pragma unroll
    for (int k = 0; k < 7; ++k) {
        const int w = w0 + k;
        cnt[k] = local;
        local += (w < NW) ? (unsigned)__popc(bm[w]) : 0u;
    }
    scan[tid] = local;
    __syncthreads();
    for (int off = 1; off < 256; off <<= 1) {
        const unsigned mine = scan[tid];
        const unsigned add  = (tid >= off) ? scan[tid - off] : 0u;
        __syncthreads();
        scan[tid] = mine + add;
        __syncthreads();
    }
    const unsigned excl = (tid > 0) ? scan[tid - 1] : 0u;
#pragma unroll
    for (int k = 0; k < 7; ++k) {
        const int w = w0 + k;
        if (w < NW) pre[w] = excl + cnt[k];
    }
    __syncthreads();
    for (int s = tid; s < SS; s += 256) {
        const int v = idb[s];
        const unsigned w = (unsigned)v >> 5, bit = (unsigned)v & 31u;
        const unsigned r = pre[w] + (unsigned)__popc(bm[w] & ((1u << bit) - 1u));
        rank_g[b * SS + s] = (unsigned short)r;
        coll[r] = (unsigned short)v;      // benign write-race: same value
    }
    __syncthreads();
    for (int i = tid; i < SS; i += 256) col_g[b * SS + i] = coll[i];
}

// ---------------------------------------------------------------------------
// Kernel B: one block per (b,t) row.
//   pass 1: vals[rank[s]] += attn[row,s] (LDS atomics) + p_gen dot
//   pass 2: for each 2048-col chunk: stream zeros (float4, branch-free),
//           barrier, then scatter the chunk's ~35 unique values as 4B
//           stores into the just-zeroed (L2-dirty) lines.
// Every output cacheline is written once by the streaming pass; scattered
// stores hit L2 (256 blocks/XCD x 8KB = 2MB < 4MB L2). No global atomics.
// ---------------------------------------------------------------------------
__global__ __launch_bounds__(256) void row_kernel(
    const float* __restrict__ attn,
    const float* __restrict__ src_proj,
    const float* __restrict__ tgt_proj,
    const unsigned short* __restrict__ rank_g,
    const unsigned short* __restrict__ col_g,
    float* __restrict__ out)
{
    __shared__ unsigned short col[SS];  // sorted columns (sentinel-padded)
    __shared__ float vals[SS];
    __shared__ int bnd[NCH + 1];
    __shared__ float wsum[4];

    const int row = blockIdx.x;     // 0 .. B*T-1
    const int b   = row >> 9;       // T = 512
    const int tid = threadIdx.x;

    for (int i = tid; i < SS; i += 256) { col[i] = col_g[b * SS + i]; vals[i] = 0.f; }
    __syncthreads();

    // ---- pass 1: accumulate vals + p_gen dot (vectorized, 1024 = 4*256) ----
    const float4*  a4p = (const float4*)(attn + (size_t)row * SS);
    const float4*  sp4 = (const float4*)(src_proj + b * SS);
    const ushort4* r4p = (const ushort4*)(rank_g + b * SS);
    const float4  a = a4p[tid];
    const float4  p = sp4[tid];
    const ushort4 r = r4p[tid];
    atomicAdd(&vals[r.x], a.x);
    atomicAdd(&vals[r.y], a.y);
    atomicAdd(&vals[r.z], a.z);
    atomicAdd(&vals[r.w], a.w);
    float acc = a.x * p.x + a.y * p.y + a.z * p.z + a.w * p.w;

    // chunk boundaries: lower_bound over sorted col (26 threads, 10 steps)
    if (tid <= NCH) {
        const unsigned short key = (unsigned short)(tid * CHUNK); // <= 51200
        int lo = 0, hi = SS;
        while (lo < hi) {
            const int mid = (lo + hi) >> 1;
            if (col[mid] < key) lo = mid + 1; else hi = mid;
        }
        bnd[tid] = lo;
    }

#pragma unroll
    for (int off = 32; off > 0; off >>= 1) acc += __shfl_down(acc, off);
    if ((tid & 63) == 0) wsum[tid >> 6] = acc;
    __syncthreads();   // vals final + bnd + wsum visible
    if (tid == 0) {
        const float x = wsum[0] + wsum[1] + wsum[2] + wsum[3] + tgt_proj[row];
        out[row] = 1.f / (1.f + expf(-x));
    }

    // ---- pass 2: chunked zero + scatter ----
    float* logits = out + (BB * TT) + (size_t)row * VV;
    const int head = (int)(((16u - (unsigned)((uintptr_t)logits & 15u)) & 15u) >> 2);
    const float4 z4 = make_float4(0.f, 0.f, 0.f, 0.f);

    for (int c = 0; c < NCH; ++c) {
        const int lo = c * CHUNK;
        const int hi = (lo + CHUNK < VV) ? lo + CHUNK : VV;
        // zero [lo,hi); (lo*4) % 16 == 0 so per-chunk misalignment == head
        if (tid < head) logits[lo + tid] = 0.f;
        const int n4 = (hi - lo - head) >> 2;
        float4* p4 = (float4*)(logits + lo + head);
        for (int i = tid; i < n4; i += 256) p4[i] = z4;
        for (int v = lo + head + (n4 << 2) + tid; v < hi; v += 256) logits[v] = 0.f;
        __syncthreads();                  // zeros of chunk c complete
        for (int idx = bnd[c] + tid; idx < bnd[c + 1]; idx += 256)
            logits[col[idx]] = vals[idx]; // hits L2-dirty lines
        // next chunk's zeros are disjoint from this scatter: no barrier
    }
}

extern "C" void kernel_launch(void* const* d_in, const int* in_sizes, int n_in,
                              void* d_out, int out_size, void* d_ws, size_t ws_size,
                              hipStream_t stream) {
    const int*   ids  = (const int*)d_in[0];    // [B,S]
    const float* attn = (const float*)d_in[1];  // [B,T,S]
    const float* src  = (const float*)d_in[2];  // [B,S,H]
    const float* tgt  = (const float*)d_in[3];  // [B,T,H]
    const float* W    = (const float*)d_in[4];  // [2H,1]
    const float* bp   = (const float*)d_in[5];  // [1]

    float* out = (float*)d_out;                 // [B*T (p_gen) | B*T*V]

    // ws layout (all 16B-aligned)
    float*          src_proj = (float*)d_ws;                        // 4096 f
    float*          tgt_proj = src_proj + BB * SS;                  // 2048 f
    unsigned short* rank_g   = (unsigned short*)(tgt_proj + BB*TT); // B*S u16
    unsigned short* col_g    = rank_g + BB * SS;                    // B*S u16

    proj_kernel<<<(BB * SS + BB * TT) / 4, 256, 0, stream>>>(
        src, tgt, W, bp, src_proj, tgt_proj);
    batch_setup<<<BB, 256, 0, stream>>>(ids, rank_g, col_g);
    row_kernel<<<BB * TT, 256, 0, stream>>>(
        attn, src_proj, tgt_proj, rank_g, col_g, out);
}